// Round 1
// baseline (433.038 us; speedup 1.0000x reference)
//
#include <hip/hip_runtime.h>
#include <math.h>

#define B_ 4096
#define L_ 50
#define D_ 200
#define A_ 14
#define S_ 30

// ---------- helpers ----------
__device__ __forceinline__ float wave_reduce_sum(float v) {
    #pragma unroll
    for (int off = 32; off > 0; off >>= 1) v += __shfl_down(v, off, 64);
    return v;   // valid in lane 0
}

__device__ __forceinline__ float block_reduce_256(float val, volatile float* red) {
    // entry sync protects red[] reuse across calls
    __syncthreads();
    val = wave_reduce_sum(val);
    if ((threadIdx.x & 63) == 0) red[threadIdx.x >> 6] = val;
    __syncthreads();
    return red[0] + red[1] + red[2] + red[3];
}

// ---------- kernel 1: anchor precompute (tiny) ----------
// ws layout (floats): hyp[A*D], kle[A*D], y2[A], lf[A]
__global__ __launch_bounds__(256) void precompute_anchors(
    const float* __restrict__ a_emb, const float* __restrict__ seed_w,
    float* __restrict__ ws)
{
    __shared__ float u[A_][D_];
    __shared__ float nrm2[A_];
    const int t = threadIdx.x;
    const int wave = t >> 6, lane = t & 63;

    for (int d = t; d < D_; d += 256) {
        for (int a = 0; a < A_; ++a) {
            float acc = 0.f;
            #pragma unroll 5
            for (int s = 0; s < S_; ++s)
                acc += a_emb[(a * S_ + s) * D_ + d] * seed_w[a * S_ + s];
            u[a][d] = acc;
        }
    }
    __syncthreads();

    for (int a = wave; a < A_; a += 4) {
        float s = 0.f;
        for (int d = lane; d < D_; d += 64) s += u[a][d] * u[a][d];
        s = wave_reduce_sum(s);
        if (lane == 0) nrm2[a] = s;
    }
    __syncthreads();

    float* hyp = ws;
    float* kle = ws + A_ * D_;
    float* y2  = ws + 2 * A_ * D_;
    float* lf  = y2 + A_;
    const float maxn = 1.0f - 1e-5f;

    for (int a = 0; a < A_; ++a) {
        float un = fmaxf(sqrtf(nrm2[a]), 1e-15f);
        float th = tanhf(un);
        float pn = fminf(th, maxn);        // |hyp_a| after proj
        float s  = pn / un;                // hyp_a = u * s
        float py2 = pn * pn;
        float kscale = 2.0f / (1.0f + py2);        // kle = hyp * kscale
        float k2 = py2 * kscale * kscale;          // |kle|^2
        if (t == 0) {
            y2[a] = py2;
            lf[a] = 1.0f / sqrtf(fmaxf(1.0f - k2, 1e-7f));
        }
        for (int d = t; d < D_; d += 256) {
            float h = u[a][d] * s;
            hyp[a * D_ + d] = h;
            kle[a * D_ + d] = h * kscale;
        }
    }
}

// ---------- kernel 2: fused per-batch-row pipeline ----------
__global__ __launch_bounds__(256) void fused_main(
    const int*   __restrict__ inputs,
    const float* __restrict__ emb,
    const float* __restrict__ M,
    const float* __restrict__ ws,
    float* __restrict__ out)
{
    __shared__ float x[L_][D_ + 1];   // +1 pad: breaks bank conflicts on per-l reads
    __shared__ float xavg[D_];
    __shared__ float v[D_];
    __shared__ float attn[L_];
    __shared__ float pvec[D_];
    __shared__ float dotpq[A_];
    __shared__ float pexp[A_];
    __shared__ float pe[A_];
    __shared__ float red[4];
    __shared__ float sums[2];

    const float* hyp = ws;
    const float* kle = ws + A_ * D_;
    const float* y2  = ws + 2 * A_ * D_;
    const float* lf  = y2 + A_;

    const int b = blockIdx.x;
    const int t = threadIdx.x;
    const int wave = t >> 6, lane = t & 63;
    const int* idx = inputs + b * L_;

    // 1) gather x_wrd tile into LDS: wave per row, lanes load float4
    for (int l = wave; l < L_; l += 4) {
        const float4* src = (const float4*)(emb + (size_t)idx[l] * D_);
        for (int q = lane; q < D_ / 4; q += 64) {
            float4 val = src[q];
            x[l][4 * q + 0] = val.x; x[l][4 * q + 1] = val.y;
            x[l][4 * q + 2] = val.z; x[l][4 * q + 3] = val.w;
        }
    }
    __syncthreads();

    // 2) x_avg = mean over L
    if (t < D_) {
        float s = 0.f;
        #pragma unroll 5
        for (int l = 0; l < L_; ++l) s += x[l][t];
        xavg[t] = s * (1.0f / (float)L_);
    }
    __syncthreads();

    // 3) v = M @ x_avg : wave per output row (coalesced M reads)
    for (int d = wave; d < D_; d += 4) {
        const float* Mr = M + d * D_;
        float s = 0.f;
        for (int e = lane; e < D_; e += 64) s += Mr[e] * xavg[e];
        s = wave_reduce_sum(s);
        if (lane == 0) v[d] = s;
    }
    __syncthreads();

    // 4) raw scores: wave per l
    for (int l = wave; l < L_; l += 4) {
        float s = 0.f;
        for (int d = lane; d < D_; d += 64) s += x[l][d] * v[d];
        s = wave_reduce_sum(s);
        if (lane == 0) attn[l] = s;
    }
    __syncthreads();

    // 5) softmax over L (wave 0; L_=50 <= 64 lanes)
    if (wave == 0) {
        float scv = (lane < L_) ? attn[lane] : -INFINITY;
        float m = scv;
        #pragma unroll
        for (int off = 32; off > 0; off >>= 1) m = fmaxf(m, __shfl_xor(m, off, 64));
        float e = (lane < L_) ? expf(scv - m) : 0.f;
        float ss = e;
        #pragma unroll
        for (int off = 32; off > 0; off >>= 1) ss += __shfl_xor(ss, off, 64);
        if (lane < L_) attn[lane] = e / ss;
    }
    __syncthreads();

    // 6) enc[d] = sum_l attn[l] * x[l][d]
    float encv = 0.f;
    if (t < D_) {
        #pragma unroll 5
        for (int l = 0; l < L_; ++l) encv += attn[l] * x[l][t];
    }

    // 7) expmap0 + proj (scalar per row)
    float n2 = block_reduce_256((t < D_) ? encv * encv : 0.f, red);
    const float maxn = 1.0f - 1e-5f;
    float un = fmaxf(sqrtf(n2), 1e-15f);
    float th = tanhf(un);
    float pn = fminf(th, maxn);
    float ps = pn / un;
    float x2 = pn * pn;          // |p|^2, needed by all threads
    if (t < D_) pvec[t] = encv * ps;
    __syncthreads();

    // 8) dot(p, hyp_a[a]) : wave per a (coalesced anchor reads)
    for (int a = wave; a < A_; a += 4) {
        const float* ha = hyp + a * D_;
        float s = 0.f;
        for (int d = lane; d < D_; d += 64) s += ha[d] * pvec[d];
        s = wave_reduce_sum(s);
        if (lane == 0) dotpq[a] = s;
    }
    __syncthreads();

    // 9) sqdist via scalars; probs_exp
    if (t < A_) {
        float dot = dotpq[t];
        float yy  = y2[t];
        float c1 = 1.0f - 2.0f * dot + yy;      // 1 + 2*xy + y2, xy = -dot
        float c2 = 1.0f - x2;
        float num2 = c1 * c1 * x2 - 2.0f * c1 * c2 * dot + c2 * c2 * yy;
        float den  = fmaxf(1.0f - 2.0f * dot + x2 * yy, 1e-15f);
        float nma  = sqrtf(fmaxf(num2, 0.f)) / den;
        float z    = fminf(nma, 1.0f - 1e-7f);
        float dist = logf((1.0f + z) / (1.0f - z));   // 2*artanh(z)
        pexp[t] = expf(-dist * dist - 0.05f);
    }
    __syncthreads();
    if (t == 0) {
        float se = 0.f, sp = 0.f;
        for (int a = 0; a < A_; ++a) { se += pexp[a]; sp += lf[a] * pexp[a]; }
        sums[0] = 1.0f / se;
        sums[1] = 1.0f / sp;
    }
    __syncthreads();
    if (t < A_) {
        float ap  = pexp[t] * sums[0];
        float pev = lf[t] * pexp[t] * sums[1];
        pe[t] = pev;
        out[B_ * D_ + b * A_ + t] = pev;                 // probs_expanded
        out[B_ * D_ + B_ * A_ + b * A_ + t] = ap;        // a_probs
    }
    __syncthreads();

    // 10) Klein barycenter -> klein_to -> logmap0
    float ko = 0.f;
    if (t < D_) {
        #pragma unroll
        for (int a = 0; a < A_; ++a) ko += kle[a * D_ + t] * pe[a];
    }
    float n2k = block_reduce_256((t < D_) ? ko * ko : 0.f, red);
    if (t < D_) {
        float denom = 1.0f + sqrtf(fmaxf(1.0f - n2k, 0.f));
        float rv = ko / denom;
        float r2 = n2k / (denom * denom);
        float rn = fmaxf(sqrtf(r2), 1e-15f);
        float z  = fminf(rn, 1.0f - 1e-7f);
        float fac = (0.5f * logf((1.0f + z) / (1.0f - z))) / rn;
        out[b * D_ + t] = fac * rv;
    }
}

extern "C" void kernel_launch(void* const* d_in, const int* in_sizes, int n_in,
                              void* d_out, int out_size, void* d_ws, size_t ws_size,
                              hipStream_t stream) {
    (void)in_sizes; (void)n_in; (void)out_size; (void)ws_size;
    const int*   inputs = (const int*)  d_in[0];
    const float* emb    = (const float*)d_in[1];
    const float* M      = (const float*)d_in[2];
    const float* a_emb  = (const float*)d_in[3];
    const float* seed_w = (const float*)d_in[4];
    float* out = (float*)d_out;
    float* ws  = (float*)d_ws;

    precompute_anchors<<<1, 256, 0, stream>>>(a_emb, seed_w, ws);
    fused_main<<<B_, 256, 0, stream>>>(inputs, emb, M, ws, out);
}

// Round 2
// 145.560 us; speedup vs baseline: 2.9750x; 2.9750x over previous
//
#include <hip/hip_runtime.h>
#include <math.h>

#define B_ 4096
#define L_ 50
#define D_ 200
#define A_ 14
#define S_ 30

// ws layout (floats)
#define WS_HYP   0
#define WS_KLE   (A_ * D_)
#define WS_Y2    (2 * A_ * D_)
#define WS_LF    (WS_Y2 + A_)
#define WS_XAVG  8192
#define WS_V     (WS_XAVG + B_ * D_)

// ---------- helpers ----------
__device__ __forceinline__ float wave_reduce_sum(float v) {
    #pragma unroll
    for (int off = 32; off > 0; off >>= 1) v += __shfl_down(v, off, 64);
    return v;   // valid in lane 0
}

// 8-wave block reduce; result broadcast to all threads
__device__ __forceinline__ float block_reduce_512(float val, volatile float* red) {
    __syncthreads();                 // protects red[] and prior LDS reads
    val = wave_reduce_sum(val);
    if ((threadIdx.x & 63) == 0) red[threadIdx.x >> 6] = val;
    __syncthreads();
    float s = 0.f;
    #pragma unroll
    for (int i = 0; i < 8; ++i) s += red[i];
    return s;
}

// ---------- kernel 0: anchor precompute (tiny) ----------
__global__ __launch_bounds__(256) void precompute_anchors(
    const float* __restrict__ a_emb, const float* __restrict__ seed_w,
    float* __restrict__ ws)
{
    __shared__ float u[A_][D_];
    __shared__ float nrm2[A_];
    const int t = threadIdx.x;
    const int wave = t >> 6, lane = t & 63;

    for (int d = t; d < D_; d += 256) {
        for (int a = 0; a < A_; ++a) {
            float acc = 0.f;
            #pragma unroll 5
            for (int s = 0; s < S_; ++s)
                acc += a_emb[(a * S_ + s) * D_ + d] * seed_w[a * S_ + s];
            u[a][d] = acc;
        }
    }
    __syncthreads();

    for (int a = wave; a < A_; a += 4) {
        float s = 0.f;
        for (int d = lane; d < D_; d += 64) s += u[a][d] * u[a][d];
        s = wave_reduce_sum(s);
        if (lane == 0) nrm2[a] = s;
    }
    __syncthreads();

    float* hyp = ws + WS_HYP;
    float* kle = ws + WS_KLE;
    float* y2  = ws + WS_Y2;
    float* lf  = ws + WS_LF;
    const float maxn = 1.0f - 1e-5f;

    for (int a = 0; a < A_; ++a) {
        float un = fmaxf(sqrtf(nrm2[a]), 1e-15f);
        float th = tanhf(un);
        float pn = fminf(th, maxn);
        float s  = pn / un;
        float py2 = pn * pn;
        float kscale = 2.0f / (1.0f + py2);
        float k2 = py2 * kscale * kscale;
        if (t == 0) {
            y2[a] = py2;
            lf[a] = 1.0f / sqrtf(fmaxf(1.0f - k2, 1e-7f));
        }
        for (int d = t; d < D_; d += 256) {
            float h = u[a][d] * s;
            hyp[a * D_ + d] = h;
            kle[a * D_ + d] = h * kscale;
        }
    }
}

// ---------- kernel 1: x_avg[b,:] = mean_l emb[idx[b,l],:] ----------
__global__ __launch_bounds__(128) void compute_xavg(
    const int* __restrict__ inputs, const float* __restrict__ emb,
    float* __restrict__ ws)
{
    float* xavg = ws + WS_XAVG;
    const int b = blockIdx.x, t = threadIdx.x;
    __shared__ int sidx[L_];
    if (t < L_) sidx[t] = inputs[b * L_ + t];
    __syncthreads();
    if (t < D_ / 2) {
        float sx = 0.f, sy = 0.f;
        #pragma unroll 10
        for (int l = 0; l < L_; ++l) {
            const float2 vv = ((const float2*)(emb + (size_t)sidx[l] * D_))[t];
            sx += vv.x; sy += vv.y;
        }
        ((float2*)(xavg + (size_t)b * D_))[t] = make_float2(sx * (1.f / L_), sy * (1.f / L_));
    }
}

// ---------- kernel 2: V = x_avg @ M^T, tiled 8 batch rows/block ----------
#define K2R 8
__global__ __launch_bounds__(256) void gemm_v(
    const float* __restrict__ M, const float* __restrict__ ws_in,
    float* __restrict__ ws_out)
{
    __shared__ float xs[K2R][D_ + 4];   // pad 4 floats: bank-spread + float4 align
    const float* xavg = ws_in + WS_XAVG;
    float* v = ws_out + WS_V;
    const int b0 = blockIdx.x * K2R;
    for (int p = threadIdx.x; p < K2R * D_; p += 256) {
        int r = p / D_, e = p % D_;
        xs[r][e] = xavg[(size_t)(b0 + r) * D_ + e];
    }
    __syncthreads();
    const int r = threadIdx.x & 7, dg = threadIdx.x >> 3;  // dg in 0..31
    const float4* xr4 = (const float4*)xs[r];
    #pragma unroll
    for (int k = 0; k < 7; ++k) {
        const int d = dg + 32 * k;
        if (d < D_) {
            const float4* Mr4 = (const float4*)(M + d * D_);
            float acc = 0.f;
            #pragma unroll 10
            for (int e = 0; e < D_ / 4; ++e) {
                float4 m4 = Mr4[e], x4 = xr4[e];
                acc += m4.x * x4.x + m4.y * x4.y + m4.z * x4.z + m4.w * x4.w;
            }
            v[(size_t)(b0 + r) * D_ + d] = acc;
        }
    }
}

// ---------- kernel 3: fused per-row pipeline (512 threads) ----------
__global__ __launch_bounds__(512, 8) void fused_main(
    const int*   __restrict__ inputs,
    const float* __restrict__ emb,
    const float* __restrict__ ws,
    float* __restrict__ out)
{
    __shared__ float x[L_][D_];       // 40000 B; rows 0/1 reused after enc
    __shared__ float attn[L_];
    __shared__ float red[8];
    __shared__ float sums[2];

    const float* hyp = ws + WS_HYP;
    const float* kle = ws + WS_KLE;
    const float* y2  = ws + WS_Y2;
    const float* lf  = ws + WS_LF;
    const float* vg  = ws + WS_V;

    const int b = blockIdx.x;
    const int t = threadIdx.x;
    const int wave = t >> 6, lane = t & 63;
    const int* idx = inputs + b * L_;

    // v kept in 4 regs/lane (same mapping for every wave)
    float vr0 = vg[(size_t)b * D_ + lane];
    float vr1 = vg[(size_t)b * D_ + lane + 64];
    float vr2 = vg[(size_t)b * D_ + lane + 128];
    float vr3 = (lane < D_ - 192) ? vg[(size_t)b * D_ + lane + 192] : 0.f;

    // 1) gather tile into LDS: wave per row
    for (int l = wave; l < L_; l += 8) {
        const float4* src = (const float4*)(emb + (size_t)idx[l] * D_);
        if (lane < D_ / 4) {
            float4 val = src[lane];
            x[l][4 * lane + 0] = val.x; x[l][4 * lane + 1] = val.y;
            x[l][4 * lane + 2] = val.z; x[l][4 * lane + 3] = val.w;
        }
    }
    __syncthreads();

    // 2) scores: wave per l, dot(x_l, v)
    for (int l = wave; l < L_; l += 8) {
        float s = x[l][lane] * vr0 + x[l][lane + 64] * vr1 + x[l][lane + 128] * vr2;
        if (lane < D_ - 192) s += x[l][lane + 192] * vr3;
        s = wave_reduce_sum(s);
        if (lane == 0) attn[l] = s;
    }
    __syncthreads();

    // 3) softmax over L (wave 0)
    if (wave == 0) {
        float scv = (lane < L_) ? attn[lane] : -INFINITY;
        float m = scv;
        #pragma unroll
        for (int off = 32; off > 0; off >>= 1) m = fmaxf(m, __shfl_xor(m, off, 64));
        float e = (lane < L_) ? expf(scv - m) : 0.f;
        float ss = e;
        #pragma unroll
        for (int off = 32; off > 0; off >>= 1) ss += __shfl_xor(ss, off, 64);
        if (lane < L_) attn[lane] = e / ss;
    }
    __syncthreads();

    // 4) enc[d]
    float encv = 0.f;
    if (t < D_) {
        #pragma unroll 10
        for (int l = 0; l < L_; ++l) encv += attn[l] * x[l][t];
    }

    // 5) expmap0 + proj
    float n2 = block_reduce_512((t < D_) ? encv * encv : 0.f, red);
    const float maxn = 1.0f - 1e-5f;
    float un = fmaxf(sqrtf(n2), 1e-15f);
    float pn = fminf(tanhf(un), maxn);
    float ps = pn / un;
    float x2 = pn * pn;
    float* pvec  = &x[0][0];          // x dead from here on
    float* dotpq = &x[1][0];
    float* pexp  = &x[1][16];
    float* pe    = &x[1][32];
    if (t < D_) pvec[t] = encv * ps;
    __syncthreads();

    // 6) dot(p, hyp_a): wave per anchor
    for (int a = wave; a < A_; a += 8) {
        const float* ha = hyp + a * D_;
        float s = ha[lane] * pvec[lane] + ha[lane + 64] * pvec[lane + 64]
                + ha[lane + 128] * pvec[lane + 128];
        if (lane < D_ - 192) s += ha[lane + 192] * pvec[lane + 192];
        s = wave_reduce_sum(s);
        if (lane == 0) dotpq[a] = s;
    }
    __syncthreads();

    // 7) sqdist scalars -> probs_exp
    if (t < A_) {
        float dot = dotpq[t];
        float yy  = y2[t];
        float c1 = 1.0f - 2.0f * dot + yy;
        float c2 = 1.0f - x2;
        float num2 = c1 * c1 * x2 - 2.0f * c1 * c2 * dot + c2 * c2 * yy;
        float den  = fmaxf(1.0f - 2.0f * dot + x2 * yy, 1e-15f);
        float nma  = sqrtf(fmaxf(num2, 0.f)) / den;
        float z    = fminf(nma, 1.0f - 1e-7f);
        float dist = logf((1.0f + z) / (1.0f - z));
        pexp[t] = expf(-dist * dist - 0.05f);
    }
    __syncthreads();
    if (t == 0) {
        float se = 0.f, sp = 0.f;
        for (int a = 0; a < A_; ++a) { se += pexp[a]; sp += lf[a] * pexp[a]; }
        sums[0] = 1.0f / se;
        sums[1] = 1.0f / sp;
    }
    __syncthreads();
    if (t < A_) {
        float ap  = pexp[t] * sums[0];
        float pev = lf[t] * pexp[t] * sums[1];
        pe[t] = pev;
        out[B_ * D_ + b * A_ + t] = pev;                 // probs_expanded
        out[B_ * D_ + B_ * A_ + b * A_ + t] = ap;        // a_probs
    }
    __syncthreads();

    // 8) Klein barycenter -> klein_to -> logmap0
    float ko = 0.f;
    if (t < D_) {
        #pragma unroll
        for (int a = 0; a < A_; ++a) ko += kle[a * D_ + t] * pe[a];
    }
    float n2k = block_reduce_512((t < D_) ? ko * ko : 0.f, red);
    if (t < D_) {
        float denom = 1.0f + sqrtf(fmaxf(1.0f - n2k, 0.f));
        float rv = ko / denom;
        float r2 = n2k / (denom * denom);
        float rn = fmaxf(sqrtf(r2), 1e-15f);
        float z  = fminf(rn, 1.0f - 1e-7f);
        float fac = (0.5f * logf((1.0f + z) / (1.0f - z))) / rn;
        out[b * D_ + t] = fac * rv;
    }
}

extern "C" void kernel_launch(void* const* d_in, const int* in_sizes, int n_in,
                              void* d_out, int out_size, void* d_ws, size_t ws_size,
                              hipStream_t stream) {
    (void)in_sizes; (void)n_in; (void)out_size; (void)ws_size;
    const int*   inputs = (const int*)  d_in[0];
    const float* emb    = (const float*)d_in[1];
    const float* M      = (const float*)d_in[2];
    const float* a_emb  = (const float*)d_in[3];
    const float* seed_w = (const float*)d_in[4];
    float* out = (float*)d_out;
    float* ws  = (float*)d_ws;

    precompute_anchors<<<1, 256, 0, stream>>>(a_emb, seed_w, ws);
    compute_xavg<<<B_, 128, 0, stream>>>(inputs, emb, ws);
    gemm_v<<<B_ / K2R, 256, 0, stream>>>(M, ws, ws);
    fused_main<<<B_, 512, 0, stream>>>(inputs, emb, ws, out);
}